// Round 1
// baseline (1010.166 us; speedup 1.0000x reference)
//
#include <hip/hip_runtime.h>
#include <hip/hip_bf16.h>

// Problem constants (from reference)
#define BB 4096
#define VV 200
#define FF 4
#define GG 80
#define RR 16
#define NLIG 7
#define TWO_PI_F 6.2831853071795864769f   // rounds to f32(2*pi)
#define ANG_STEP 0.39269908169872414f     // f32(2*pi/16)

// ---------------------------------------------------------------------------
// Kernel A: per-sample b -> gaussian agg over (f,g,r), conv GEMV + relu + max
// over rotations, fc1 + relu. One block per b, 320 threads = (f,g).
// ---------------------------------------------------------------------------
__global__ __launch_bounds__(320) void masif_main(
    const float* __restrict__ xin,      // [B,V,F]
    const float* __restrict__ rho,      // [B,V]
    const float* __restrict__ theta,    // [B,V]
    const float* __restrict__ mask,     // [B,V]
    const float* __restrict__ mu_rho,   // [F,G]
    const float* __restrict__ mu_theta, // [F,G]
    const float* __restrict__ sigma_rho,   // [F,G]
    const float* __restrict__ sigma_theta, // [F,G]
    const float* __restrict__ conv_W,   // [F,G,G]
    const float* __restrict__ conv_b,   // [F,G]
    const float* __restrict__ fc1_W,    // [G, F*G]
    const float* __restrict__ fc1_b,    // [G]
    float* __restrict__ xbuf)           // [B,G] out
{
    const int b = blockIdx.x;
    const int t = threadIdx.x;
    const int f = t / GG;   // 0..3
    const int g = t % GG;   // 0..79

    __shared__ float th_s[VV][RR];    // wrapped theta + ang  (12.8 KB)
    __shared__ float mx_s[VV][FF];    // mask * x             (3.2 KB)
    __shared__ float rho_s[VV];       // (0.8 KB)
    __shared__ float aggL[FF][RR][GG];// (20.5 KB)
    __shared__ float desc_s[FF * GG]; // (1.3 KB)

    // ---- stage per-vertex data ----
    for (int v = t; v < VV; v += 320) {
        const int idx = b * VV + v;
        float th = theta[idx];
        float m  = mask[idx];
        rho_s[v] = rho[idx];
        #pragma unroll
        for (int r = 0; r < RR; ++r) {
            float a = th + ANG_STEP * (float)r;     // in [0, 4*pi)
            if (a >= TWO_PI_F) a -= TWO_PI_F;       // exact (Sterbenz) == fmod
            th_s[v][r] = a;
        }
        float4 xv = *reinterpret_cast<const float4*>(&xin[idx * 4]);
        mx_s[v][0] = m * xv.x;
        mx_s[v][1] = m * xv.y;
        mx_s[v][2] = m * xv.z;
        mx_s[v][3] = m * xv.w;
    }

    // per-(f,g) parameters
    const float mr  = mu_rho[f * GG + g];
    const float mt  = mu_theta[f * GG + g];
    const float sr  = sigma_rho[f * GG + g];
    const float st  = sigma_theta[f * GG + g];
    const float nisr = -1.0f / (sr * sr + 1e-5f);
    const float nist = -1.0f / (st * st + 1e-5f);

    __syncthreads();

    // ---- gaussian aggregation: acc[r] = sum_v exp(ar + at_r) * mask*x ----
    float acc[RR];
    #pragma unroll
    for (int r = 0; r < RR; ++r) acc[r] = 0.0f;

    for (int v = 0; v < VV; ++v) {
        const float d   = rho_s[v] - mr;
        const float ar  = d * d * nisr;
        const float mxv = mx_s[v][f];
        const float4* thv = reinterpret_cast<const float4*>(&th_s[v][0]);
        float4 t4[4];
        t4[0] = thv[0]; t4[1] = thv[1]; t4[2] = thv[2]; t4[3] = thv[3];
        const float* thp = reinterpret_cast<const float*>(t4);
        #pragma unroll
        for (int r = 0; r < RR; ++r) {
            float dt  = thp[r] - mt;
            float arg = fmaf(dt * dt, nist, ar);
            acc[r] = fmaf(__expf(arg), mxv, acc[r]);
        }
    }

    #pragma unroll
    for (int r = 0; r < RR; ++r) aggL[f][r][g] = acc[r];

    __syncthreads();

    // ---- conv GEMV + relu + max over rotations: thread = (f, j=g) ----
    const int j = g;
    float racc[RR];
    const float cb = conv_b[f * GG + j];
    #pragma unroll
    for (int r = 0; r < RR; ++r) racc[r] = cb;
    for (int gg = 0; gg < GG; ++gg) {
        const float w = conv_W[(f * GG + gg) * GG + j];
        #pragma unroll
        for (int r = 0; r < RR; ++r)
            racc[r] = fmaf(aggL[f][r][gg], w, racc[r]);
    }
    float mxr = racc[0];
    #pragma unroll
    for (int r = 1; r < RR; ++r) mxr = fmaxf(mxr, racc[r]);
    desc_s[f * GG + j] = fmaxf(mxr, 0.0f);

    __syncthreads();

    // ---- fc1 + relu (80 outputs, dot over 320) ----
    if (t < GG) {
        float a1 = fc1_b[t];
        #pragma unroll 4
        for (int k = 0; k < FF * GG; ++k)
            a1 = fmaf(desc_s[k], fc1_W[t * (FF * GG) + k], a1);
        xbuf[b * GG + t] = fmaxf(a1, 0.0f);
    }
}

// ---------------------------------------------------------------------------
// Kernel B: partial gram. 64 blocks x 64 samples each; 256 threads own 5x5
// tiles of the 80x80 outer-product accumulation. Deterministic.
// ---------------------------------------------------------------------------
__global__ __launch_bounds__(256) void gram_partial(
    const float* __restrict__ xbuf,   // [B,G]
    float* __restrict__ gpart)        // [64, G*G]
{
    const int blk = blockIdx.x;   // 0..63
    const int t = threadIdx.x;
    __shared__ float xs[64][GG];

    for (int i = t; i < 64 * GG; i += 256) {
        int bb = i / GG, jj = i % GG;
        xs[bb][jj] = xbuf[(blk * 64 + bb) * GG + jj];
    }
    __syncthreads();

    const int ti = t / 16, tj = t % 16;   // 16x16 grid of 5x5 tiles
    float acc[5][5];
    #pragma unroll
    for (int u = 0; u < 5; ++u)
        #pragma unroll
        for (int w = 0; w < 5; ++w) acc[u][w] = 0.0f;

    for (int bb = 0; bb < 64; ++bb) {
        float xi[5], xj[5];
        #pragma unroll
        for (int u = 0; u < 5; ++u) { xi[u] = xs[bb][ti * 5 + u]; xj[u] = xs[bb][tj * 5 + u]; }
        #pragma unroll
        for (int u = 0; u < 5; ++u)
            #pragma unroll
            for (int w = 0; w < 5; ++w)
                acc[u][w] = fmaf(xi[u], xj[w], acc[u][w]);
    }

    #pragma unroll
    for (int u = 0; u < 5; ++u)
        #pragma unroll
        for (int w = 0; w < 5; ++w)
            gpart[blk * (GG * GG) + (ti * 5 + u) * GG + (tj * 5 + w)] = acc[u][w];
}

// ---------------------------------------------------------------------------
// Kernel C: reduce gram partials (ordered -> deterministic), fc2+relu, fco.
// ---------------------------------------------------------------------------
__global__ __launch_bounds__(256) void final_head(
    const float* __restrict__ gpart,  // [64, G*G]
    const float* __restrict__ fc2_W,  // [64, G*G]
    const float* __restrict__ fc2_b,  // [64]
    const float* __restrict__ fco_W,  // [NLIG, 64]
    const float* __restrict__ fco_b,  // [NLIG]
    float* __restrict__ out)          // [NLIG]
{
    const int t = threadIdx.x;
    __shared__ float gram[GG * GG];   // 25.6 KB
    __shared__ float hp[4][64];
    __shared__ float h[64];

    for (int i = t; i < GG * GG; i += 256) {
        float s = 0.0f;
        for (int p = 0; p < 64; ++p) s += gpart[p * (GG * GG) + i];
        gram[i] = s * (1.0f / 4096.0f);
    }
    __syncthreads();

    {
        const int jj = t & 63, part = t >> 6;    // 4 partial splits over k
        float a = 0.0f;
        const int k0 = part * 1600, k1 = k0 + 1600;
        for (int k = k0; k < k1; ++k)
            a = fmaf(gram[k], fc2_W[jj * (GG * GG) + k], a);
        hp[part][jj] = a;
    }
    __syncthreads();
    if (t < 64)
        h[t] = fmaxf(hp[0][t] + hp[1][t] + hp[2][t] + hp[3][t] + fc2_b[t], 0.0f);
    __syncthreads();

    if (t < NLIG) {
        float a = fco_b[t];
        #pragma unroll
        for (int jj = 0; jj < 64; ++jj)
            a = fmaf(h[jj], fco_W[t * 64 + jj], a);
        out[t] = a;
    }
}

// ---------------------------------------------------------------------------
extern "C" void kernel_launch(void* const* d_in, const int* in_sizes, int n_in,
                              void* d_out, int out_size, void* d_ws, size_t ws_size,
                              hipStream_t stream) {
    const float* input_feat  = (const float*)d_in[0];
    const float* rho         = (const float*)d_in[1];
    const float* theta       = (const float*)d_in[2];
    const float* mask        = (const float*)d_in[3];
    const float* mu_rho      = (const float*)d_in[4];
    const float* mu_theta    = (const float*)d_in[5];
    const float* sigma_rho   = (const float*)d_in[6];
    const float* sigma_theta = (const float*)d_in[7];
    const float* conv_W      = (const float*)d_in[8];
    const float* conv_b      = (const float*)d_in[9];
    const float* fc1_W       = (const float*)d_in[10];
    const float* fc1_b       = (const float*)d_in[11];
    const float* fc2_W       = (const float*)d_in[12];
    const float* fc2_b       = (const float*)d_in[13];
    const float* fco_W       = (const float*)d_in[14];
    const float* fco_b       = (const float*)d_in[15];

    float* xbuf  = (float*)d_ws;                                    // [B,G]  1.31 MB
    float* gpart = (float*)((char*)d_ws + (size_t)BB * GG * 4);     // [64,G*G] 1.64 MB

    masif_main<<<BB, 320, 0, stream>>>(input_feat, rho, theta, mask,
                                       mu_rho, mu_theta, sigma_rho, sigma_theta,
                                       conv_W, conv_b, fc1_W, fc1_b, xbuf);
    gram_partial<<<64, 256, 0, stream>>>(xbuf, gpart);
    final_head<<<1, 256, 0, stream>>>(gpart, fc2_W, fc2_b, fco_W, fco_b,
                                      (float*)d_out);
}